// Round 2
// baseline (325.558 us; speedup 1.0000x reference)
//
#include <hip/hip_runtime.h>
#include <math.h>

#define PP 3
#define HH 4
#define DD 32
#define FF 128   // H*D
#define INF_ 128 // input feature dim
#define NEG_SLOPE 0.2f

#define BSHIFT 9          // bucket = dst >> 9  (512 nodes/bucket)
#define BW 512            // nodes per bucket
#define BCAP 10240        // max edges per bucket (mean ~8700 -> 17 sigma headroom)
#define ACH 8             // edge rounds per thread in kA (chunk = 2048 edges)

// Column permutation for featb/zb16 rows: word j holds cols (C(j), C(j)+16),
// C(j) = 32*(j>>4) + (j&15). Both cols of a word share head j>>4.
// k6's W1pack applies the matching k-permutation sigma.

typedef __bf16 bf16x8 __attribute__((ext_vector_type(8)));
typedef float f32x4 __attribute__((ext_vector_type(4)));

#define LO16F(u) __uint_as_float((u) << 16)
#define HI16F(u) __uint_as_float((u) & 0xFFFF0000u)

__device__ __forceinline__ unsigned int bf16pair(float x, float y) {
    unsigned int a = __float_as_uint(x);
    unsigned int b = __float_as_uint(y);
    a = (a + 0x7FFFu + ((a >> 16) & 1u)) >> 16;   // RNE round to bf16
    b = (b + 0x7FFFu + ((b >> 16) & 1u)) >> 16;
    return a | (b << 16);
}

// KH: h fp32 -> bf16 (once); also zeroes gcur (replaces a memset dispatch)
__global__ __launch_bounds__(256) void kh_conv(const float* __restrict__ h,
                                               unsigned short* __restrict__ hb16,
                                               int* __restrict__ gcur,
                                               int total4) {
    int i = blockIdx.x * 256 + threadIdx.x;
    if (i < PP * 128) gcur[i] = 0;
    if (i < total4) {
        float4 v = *(const float4*)&h[(size_t)i * 4];
        unsigned int lo = bf16pair(v.x, v.y);
        unsigned int hi = bf16pair(v.z, v.w);
        *(uint2*)&hb16[(size_t)i * 4] = make_uint2(lo, hi);
    }
}

// KW: pack nmat 128x128 fp32 matrices into B-fragment order for
// mfma_f32_16x16x32_bf16: B[k][n], n=lane&15, k=quad*8+j.
// perm!=0: apply sigma(k) = 32*((k>>1)>>4) + ((k>>1)&15) + 16*(k&1) to the
// k-row index (matches the permuted zb16 word layout).
__global__ __launch_bounds__(256) void kw_pack(const float* __restrict__ W,
                                               unsigned short* __restrict__ Wpack,
                                               int nmat, int perm) {
    int idx = blockIdx.x * 256 + threadIdx.x;
    if (idx >= nmat * 8 * 4 * 64) return;
    int lane = idx & 63;
    int ks = (idx >> 6) & 3;
    int nt = (idx >> 8) & 7;
    int m  = idx >> 11;
    int n  = nt * 16 + (lane & 15);
    int k0 = ks * 32 + (lane >> 4) * 8;
    const float* Wp = W + (size_t)m * INF_ * FF;
    float rowv[8];
#pragma unroll
    for (int i = 0; i < 8; ++i) {
        int k = k0 + i;
        if (perm) {
            int w = k >> 1;
            k = 32 * (w >> 4) + (w & 15) + 16 * (k & 1);
        }
        rowv[i] = Wp[(size_t)k * FF + n];
    }
    unsigned int u0 = bf16pair(rowv[0], rowv[1]);
    unsigned int u1 = bf16pair(rowv[2], rowv[3]);
    unsigned int u2 = bf16pair(rowv[4], rowv[5]);
    unsigned int u3 = bf16pair(rowv[6], rowv[7]);
    *(uint4*)&Wpack[(size_t)idx * 8] = make_uint4(u0, u1, u2, u3);
}

// K1: feat[p] = h @ W[p] via bf16 MFMA. 4 waves/block; wave = 16 rows x 128 cols.
// featb written in permuted word layout: word t16+16*np = pair(acc[2np], acc[2np+1])
// -> all-lane dense stores, no shuffles in the pack.
__global__ __launch_bounds__(256) void k1_mfma(const unsigned short* __restrict__ hb16,
                        const unsigned short* __restrict__ Wpack,
                        const float* __restrict__ al, const float* __restrict__ ar,
                        unsigned int* __restrict__ featb, float* __restrict__ el,
                        float* __restrict__ er, int N) {
    int l = threadIdx.x & 63;
    int wu = threadIdx.x >> 6;
    int p = blockIdx.y;
    int rowbase = blockIdx.x * 64 + wu * 16;
    if (rowbase >= N) return;
    int q = l >> 4;
    int t16 = l & 15;
    int arow = rowbase + t16; if (arow > N - 1) arow = N - 1;
    const unsigned short* hrow = hb16 + (size_t)arow * INF_ + q * 8;
    const unsigned short* wp = Wpack + (size_t)p * 8 * 4 * 64 * 8;

    f32x4 acc[8];
#pragma unroll
    for (int i = 0; i < 8; ++i) acc[i] = (f32x4){0.f, 0.f, 0.f, 0.f};

#pragma unroll
    for (int ks = 0; ks < 4; ++ks) {
        bf16x8 av = *(const bf16x8*)&hrow[ks * 32];
#pragma unroll
        for (int nt = 0; nt < 8; ++nt) {
            bf16x8 bv = *(const bf16x8*)&wp[(((size_t)nt * 4 + ks) * 64 + l) * 8];
            acc[nt] = __builtin_amdgcn_mfma_f32_16x16x32_bf16(av, bv, acc[nt], 0, 0, 0);
        }
    }

    float alv[8], arv[8];
#pragma unroll
    for (int nt = 0; nt < 8; ++nt) {
        int cc = (nt & 1) * 16 + t16;
        alv[nt] = al[((size_t)p * HH + (nt >> 1)) * DD + cc];
        arv[nt] = ar[((size_t)p * HH + (nt >> 1)) * DD + cc];
    }
    float elp[4][4], erp[4][4];
#pragma unroll
    for (int r = 0; r < 4; ++r)
#pragma unroll
        for (int hd = 0; hd < 4; ++hd) { elp[r][hd] = 0.f; erp[r][hd] = 0.f; }
#pragma unroll
    for (int nt = 0; nt < 8; ++nt)
#pragma unroll
        for (int r = 0; r < 4; ++r) {
            elp[r][nt >> 1] = fmaf(acc[nt][r], alv[nt], elp[r][nt >> 1]);
            erp[r][nt >> 1] = fmaf(acc[nt][r], arv[nt], erp[r][nt >> 1]);
        }
#pragma unroll
    for (int r = 0; r < 4; ++r)
#pragma unroll
        for (int hd = 0; hd < 4; ++hd) {
#pragma unroll
            for (int off = 8; off >= 1; off >>= 1) {
                elp[r][hd] += __shfl_xor(elp[r][hd], off);
                erp[r][hd] += __shfl_xor(erp[r][hd], off);
            }
        }

#pragma unroll
    for (int r = 0; r < 4; ++r) {
        int row = rowbase + q * 4 + r;
        bool vr = row < N;
        if (vr) {
            unsigned int* frow = featb + ((size_t)p * N + row) * 64;
#pragma unroll
            for (int np = 0; np < 4; ++np)
                frow[t16 + 16 * np] = bf16pair(acc[2 * np][r], acc[2 * np + 1][r]);
            if (t16 == 0) {
#pragma unroll
                for (int hd = 0; hd < 4; ++hd) {
                    el[((size_t)p * N + row) * HH + hd] = elp[r][hd];
                    er[((size_t)p * N + row) * HH + hd] = erp[r][hd];
                }
            }
        }
    }
}

// KA: bucket-partition edges by dst>>9. Per 2048-edge block: LDS histogram,
// one global atomicAdd per bucket reserves a dense run, edges written packed
// (src<<9 | dst&511) 4B each.
__global__ __launch_bounds__(256) void kA_bucket(const int* __restrict__ src,
        const int* __restrict__ dst, int* __restrict__ gcur,
        unsigned int* __restrict__ barr, int E) {
    __shared__ int cnt[128];
    __shared__ int gbase[128];
    int p = blockIdx.y;
    int t = threadIdx.x;
    int base = blockIdx.x * (ACH * 256);
    const int* sp = src + (size_t)p * E;
    const int* dp = dst + (size_t)p * E;
    if (t < 128) cnt[t] = 0;
    __syncthreads();
    int sv[ACH], dv[ACH], rv[ACH];
    bool val[ACH];
#pragma unroll
    for (int j = 0; j < ACH; ++j) {
        int idx = base + j * 256 + t;
        val[j] = idx < E;
        int ci = val[j] ? idx : (E - 1);
        dv[j] = dp[ci];
        sv[j] = sp[ci];
    }
#pragma unroll
    for (int j = 0; j < ACH; ++j)
        rv[j] = val[j] ? atomicAdd(&cnt[dv[j] >> BSHIFT], 1) : 0;
    __syncthreads();
    if (t < 128) gbase[t] = atomicAdd(&gcur[p * 128 + t], cnt[t]);
    __syncthreads();
#pragma unroll
    for (int j = 0; j < ACH; ++j) {
        if (val[j]) {
            int b = dv[j] >> BSHIFT;
            int posn = gbase[b] + rv[j];
            if (posn >= BCAP) posn = BCAP - 1;
            barr[(size_t)(p * 128 + b) * BCAP + posn] =
                ((unsigned int)sv[j] << BSHIFT) | (unsigned int)(dv[j] & (BW - 1));
        }
    }
}

// KScan: exclusive scan of per-bucket counts -> bucket bases; offs[N]=E.
__global__ __launch_bounds__(128) void kscan_buckets(const int* __restrict__ gcur,
        int* __restrict__ bukbase, int* __restrict__ offs, int N, int E, int nbuk) {
    __shared__ int sc[128];
    int t = threadIdx.x;
    for (int p = 0; p < PP; ++p) {
        int v = (t < nbuk) ? gcur[p * 128 + t] : 0;
        sc[t] = v;
        __syncthreads();
        for (int off = 1; off < 128; off <<= 1) {
            int u = (t >= off) ? sc[t - off] : 0;
            __syncthreads();
            sc[t] += u;
            __syncthreads();
        }
        if (t < nbuk) bukbase[p * 128 + t] = sc[t] - v;
        if (t == 0) offs[(size_t)p * (N + 1) + N] = E;
        __syncthreads();
    }
}

// KB: per-(bucket,path) CSR build entirely in LDS.
__global__ __launch_bounds__(512) void kB_build(const unsigned int* __restrict__ barr,
        const int* __restrict__ gcur, const int* __restrict__ bukbase,
        int* __restrict__ offs, int* __restrict__ csr, int N, int E) {
    __shared__ int cnt[BW];
    __shared__ int curs[BW];
    __shared__ int slice[BCAP];   // 40 KB
    int p = blockIdx.y, b = blockIdx.x;
    int t = threadIdx.x;
    int n0 = b << BSHIFT;
    int ncnt = N - n0; if (ncnt > BW) ncnt = BW;
    int ecnt = gcur[p * 128 + b]; if (ecnt > BCAP) ecnt = BCAP;
    int gb = bukbase[p * 128 + b];
    const unsigned int* ba = barr + (size_t)(p * 128 + b) * BCAP;
    cnt[t] = 0;
    __syncthreads();
    for (int i = t; i < ecnt; i += BW)
        atomicAdd(&cnt[ba[i] & (BW - 1u)], 1);
    __syncthreads();
    int myc = (t < ncnt) ? cnt[t] : 0;
    slice[t] = myc;
    __syncthreads();
    for (int off = 1; off < BW; off <<= 1) {
        int v = (t >= off) ? slice[t - off] : 0;
        __syncthreads();
        slice[t] += v;
        __syncthreads();
    }
    int excl = slice[t] - myc;
    if (t < ncnt) {
        curs[t] = excl;
        offs[(size_t)p * (N + 1) + n0 + t] = gb + excl;
    }
    __syncthreads();
    for (int i = t; i < ecnt; i += BW) {
        unsigned int v = ba[i];
        int pos = atomicAdd(&curs[v & (BW - 1u)], 1);
        slice[pos] = (int)(v >> BSHIFT);
    }
    __syncthreads();
    for (int i = t; i < ecnt; i += BW)
        csr[(size_t)p * E + gb + i] = slice[i];
}

// K5: per-(node,path) single-pass softmax aggregation, quarter-wave scheme.
// 4 edges in flight per wave load-instruction: lane (q=l>>4, t=l&15) gathers
// a dwordx4 = words 4t..4t+3 (all share head t>>2 under the column
// permutation) of edge (tt+q)'s featb row, accumulating 8 cols in registers.
// Per 8-edge group: 2 shfl + 2 dwordx4 gathers + 2 LDS weight reads (vs 8/8/8
// scalar before), 32-bit saddr addressing. Tail edges (l >= cnt) get weight 0
// and gather row 0 (L2-hot) -- branch-free remainder, no extra HBM fetch.
// Epilogue: butterfly reduce across quarters (xor 16/32); lane writes word
// 4t+q -> identical z/zb16 values and layout as before.
__global__ __launch_bounds__(256) void k5_aggregate(const unsigned int* __restrict__ featb,
                             const float* __restrict__ el, const float* __restrict__ er,
                             const float* __restrict__ bias,
                             const int* __restrict__ offs, const int* __restrict__ csr,
                             float* __restrict__ z, unsigned int* __restrict__ zb16,
                             int N, int E) {
    __shared__ float wbuf[4][64][HH];   // 4 KB
    int w = threadIdx.x >> 6, l = threadIdx.x & 63;
    int n = blockIdx.x * 4 + w;
    int p = blockIdx.y;
    if (n >= N) return;
    int q = l >> 4;          // quarter: which edge of a 4-group this lane works
    int t = l & 15;          // position in quarter: owns words 4t..4t+3
    int hd = t >> 2;         // head shared by words 4t..4t+3
    const float* elp = el + (size_t)p * N * HH;
    const float* erp = er + (size_t)p * N * HH;
    float4 rv = *(const float4*)&erp[(size_t)n * HH];
    int j0 = offs[(size_t)p * (N + 1) + n];
    int j1 = offs[(size_t)p * (N + 1) + n + 1];
    const int* cs = csr + (size_t)p * E;
    const char* fpb = (const char*)(featb + (size_t)p * N * 64);
    float a00 = 0.f, a01 = 0.f, a10 = 0.f, a11 = 0.f;
    float a20 = 0.f, a21 = 0.f, a30 = 0.f, a31 = 0.f;
    float sumw = 0.f;
    for (int base = j0; base < j1; base += 64) {
        int rem = j1 - base;
        int cnt = rem > 64 ? 64 : rem;
        int mysn = (l < cnt) ? cs[base + l] : 0;
        // el gather: 16B row, 32-bit byte offset -> saddr form
        float4 ev = *(const float4*)((const char*)elp + ((unsigned)mysn << 4));
        float4 wv;
        float e;
        e = ev.x + rv.x; e = fmaxf(e, NEG_SLOPE * e); wv.x = __expf(e);
        e = ev.y + rv.y; e = fmaxf(e, NEG_SLOPE * e); wv.y = __expf(e);
        e = ev.z + rv.z; e = fmaxf(e, NEG_SLOPE * e); wv.z = __expf(e);
        e = ev.w + rv.w; e = fmaxf(e, NEG_SLOPE * e); wv.w = __expf(e);
        if (l >= cnt) { wv.x = 0.f; wv.y = 0.f; wv.z = 0.f; wv.w = 0.f; }
        *(float4*)&wbuf[w][l][0] = wv;
        for (int tt = 0; tt < cnt; tt += 8) {
            int e0 = tt + q;
            int e1 = e0 + 4;
            int s0 = __shfl(mysn, e0);
            int s1 = __shfl(mysn, e1);
            // byte offset = s*256 + t*16, computed in 32-bit (saddr form)
            unsigned b0 = ((unsigned)(s0 << 4) + (unsigned)t) << 4;
            unsigned b1 = ((unsigned)(s1 << 4) + (unsigned)t) << 4;
            uint4 v0 = *(const uint4*)(fpb + b0);
            uint4 v1 = *(const uint4*)(fpb + b1);
            float w0 = wbuf[w][e0][hd];
            float w1 = wbuf[w][e1][hd];
            a00 = fmaf(w0, LO16F(v0.x), a00); a01 = fmaf(w0, HI16F(v0.x), a01);
            a10 = fmaf(w0, LO16F(v0.y), a10); a11 = fmaf(w0, HI16F(v0.y), a11);
            a20 = fmaf(w0, LO16F(v0.z), a20); a21 = fmaf(w0, HI16F(v0.z), a21);
            a30 = fmaf(w0, LO16F(v0.w), a30); a31 = fmaf(w0, HI16F(v0.w), a31);
            a00 = fmaf(w1, LO16F(v1.x), a00); a01 = fmaf(w1, HI16F(v1.x), a01);
            a10 = fmaf(w1, LO16F(v1.y), a10); a11 = fmaf(w1, HI16F(v1.y), a11);
            a20 = fmaf(w1, LO16F(v1.z), a20); a21 = fmaf(w1, HI16F(v1.z), a21);
            a30 = fmaf(w1, LO16F(v1.w), a30); a31 = fmaf(w1, HI16F(v1.w), a31);
            sumw += w0 + w1;
        }
    }
    // reduce partial sums across the 4 quarters (lanes l^16, l^32, l^48)
#pragma unroll
    for (int off = 16; off <= 32; off <<= 1) {
        a00 += __shfl_xor(a00, off); a01 += __shfl_xor(a01, off);
        a10 += __shfl_xor(a10, off); a11 += __shfl_xor(a11, off);
        a20 += __shfl_xor(a20, off); a21 += __shfl_xor(a21, off);
        a30 += __shfl_xor(a30, off); a31 += __shfl_xor(a31, off);
        sumw += __shfl_xor(sumw, off);
    }
    float inv = 1.f / sumw;
    int word = 4 * t + q;                 // bijective over lanes: lane writes word 4t+q
    int ca = 32 * hd + (word & 15);       // cols (ca, ca+16)
    float s0v = (q == 0) ? a00 : (q == 1) ? a10 : (q == 2) ? a20 : a30;
    float s1v = (q == 0) ? a01 : (q == 1) ? a11 : (q == 2) ? a21 : a31;
    float z0 = s0v * inv + bias[p * FF + ca];
    float z1 = s1v * inv + bias[p * FF + ca + 16];
    z0 = z0 > 0.f ? z0 : __expf(z0) - 1.f;
    z1 = z1 > 0.f ? z1 : __expf(z1) - 1.f;
    size_t zb = ((size_t)p * N + n) * FF;
    z[zb + ca] = z0;
    z[zb + ca + 16] = z1;
    zb16[((size_t)p * N + n) * 64 + word] = bf16pair(z0, z1);
}

// K6: s[n,p] = tanh(z @ W1 + b1) @ W2 via bf16 MFMA (W1pack k-permuted to
// match zb16 word layout), summed per block.
__global__ __launch_bounds__(256) void k6_mfma(const unsigned int* __restrict__ zb16,
                        const unsigned short* __restrict__ W1pack,
                        const float* __restrict__ b1, const float* __restrict__ W2,
                        float* __restrict__ partials, int N) {
    __shared__ float wsum[4];
    int l = threadIdx.x & 63;
    int wu = threadIdx.x >> 6;
    int p = blockIdx.y;
    int rowbase = blockIdx.x * 64 + wu * 16;
    float ssum = 0.f;
    if (rowbase < N) {
        int q = l >> 4;
        int t16 = l & 15;
        int arow = rowbase + t16; if (arow > N - 1) arow = N - 1;
        const unsigned short* zrow =
            (const unsigned short*)(zb16 + ((size_t)p * N + arow) * 64) + q * 8;

        f32x4 acc[8];
#pragma unroll
        for (int i = 0; i < 8; ++i) acc[i] = (f32x4){0.f, 0.f, 0.f, 0.f};
#pragma unroll
        for (int ks = 0; ks < 4; ++ks) {
            bf16x8 av = *(const bf16x8*)&zrow[ks * 32];
#pragma unroll
            for (int nt = 0; nt < 8; ++nt) {
                bf16x8 bv = *(const bf16x8*)&W1pack[(((size_t)nt * 4 + ks) * 64 + l) * 8];
                acc[nt] = __builtin_amdgcn_mfma_f32_16x16x32_bf16(av, bv, acc[nt], 0, 0, 0);
            }
        }
        float b1v[8], w2v[8];
#pragma unroll
        for (int nt = 0; nt < 8; ++nt) {
            int col = nt * 16 + t16;
            b1v[nt] = b1[col];
            w2v[nt] = W2[col];
        }
        float rowsum[4] = {0.f, 0.f, 0.f, 0.f};
#pragma unroll
        for (int nt = 0; nt < 8; ++nt)
#pragma unroll
            for (int r = 0; r < 4; ++r) {
                float a = acc[nt][r] + b1v[nt];
                float e = __expf(2.f * a);
                float t = 1.f - 2.f * __builtin_amdgcn_rcpf(e + 1.f);
                rowsum[r] = fmaf(t, w2v[nt], rowsum[r]);
            }
#pragma unroll
        for (int r = 0; r < 4; ++r) {
            int row = rowbase + q * 4 + r;
            ssum += (row < N) ? rowsum[r] : 0.f;
        }
#pragma unroll
        for (int off = 32; off >= 1; off >>= 1) ssum += __shfl_xor(ssum, off);
    }
    if (l == 0) wsum[wu] = ssum;
    __syncthreads();
    if (threadIdx.x == 0)
        partials[(size_t)p * gridDim.x + blockIdx.x] = wsum[0] + wsum[1] + wsum[2] + wsum[3];
}

// K7: reduce partials -> w[p] mean -> beta softmax. one block, 3 waves.
__global__ void k7_beta(const float* __restrict__ partials, float* __restrict__ beta,
                        int nblk, int N) {
    __shared__ float wl[3];
    int p = threadIdx.x >> 6, l = threadIdx.x & 63;
    float s = 0.f;
    for (int i = l; i < nblk; i += 64) s += partials[(size_t)p * nblk + i];
    for (int off = 32; off >= 1; off >>= 1) s += __shfl_xor(s, off);
    if (l == 0) wl[p] = s / (float)N;
    __syncthreads();
    if (threadIdx.x == 0) {
        float m = fmaxf(wl[0], fmaxf(wl[1], wl[2]));
        float e0 = __expf(wl[0] - m), e1 = __expf(wl[1] - m), e2 = __expf(wl[2] - m);
        float inv = 1.f / (e0 + e1 + e2);
        beta[0] = e0 * inv; beta[1] = e1 * inv; beta[2] = e2 * inv;
    }
}

// K8: out[n,:] = sum_p beta[p] * z[p][n,:]  (fp32, float4 vectorized)
__global__ void k8_combine(const float* __restrict__ z, const float* __restrict__ beta,
                           float* __restrict__ out, int N) {
    size_t i = (size_t)blockIdx.x * 256 + threadIdx.x;
    size_t tot4 = (size_t)N * FF / 4;
    if (i < tot4) {
        float b0 = beta[0], b1 = beta[1], b2 = beta[2];
        const float4* z4 = (const float4*)z;
        float4 a = z4[i], b = z4[tot4 + i], c = z4[2 * tot4 + i];
        float4 o;
        o.x = b0 * a.x + b1 * b.x + b2 * c.x;
        o.y = b0 * a.y + b1 * b.y + b2 * c.y;
        o.z = b0 * a.z + b1 * b.z + b2 * c.z;
        o.w = b0 * a.w + b1 * b.w + b2 * c.w;
        ((float4*)out)[i] = o;
    }
}

extern "C" void kernel_launch(void* const* d_in, const int* in_sizes, int n_in,
                              void* d_out, int out_size, void* d_ws, size_t ws_size,
                              hipStream_t stream) {
    const float* h    = (const float*)d_in[0];
    const float* W    = (const float*)d_in[1];
    const float* al   = (const float*)d_in[2];
    const float* ar   = (const float*)d_in[3];
    const float* bias = (const float*)d_in[4];
    const float* W1   = (const float*)d_in[5];
    const float* b1   = (const float*)d_in[6];
    const float* W2   = (const float*)d_in[7];
    const int*   src  = (const int*)d_in[8];
    const int*   dst  = (const int*)d_in[9];
    float* out = (float*)d_out;

    int N = in_sizes[0] / INF_;
    int E = in_sizes[8] / PP;
    int nbuk = (N + BW - 1) >> BSHIFT;

    char* ws = (char*)d_ws;
    size_t off = 0;
    auto take = [&](size_t bytes) -> void* {
        off = (off + 255) & ~(size_t)255;
        void* ptr = ws + off;
        off += bytes;
        return ptr;
    };
    unsigned int* featb = (unsigned int*)take((size_t)PP * N * 64 * sizeof(unsigned int));
    float* z        = (float*)take((size_t)PP * N * FF * sizeof(float));
    unsigned int* zb16 = (unsigned int*)take((size_t)PP * N * 64 * sizeof(unsigned int));
    float* el       = (float*)take((size_t)PP * N * HH * sizeof(float));
    float* er       = (float*)take((size_t)PP * N * HH * sizeof(float));
    int*   offs     = (int*)take((size_t)PP * (N + 1) * sizeof(int));
    int*   csr      = (int*)take((size_t)PP * E * sizeof(int));
    unsigned int* barr = (unsigned int*)take((size_t)PP * 128 * BCAP * sizeof(unsigned int));
    int*   gcur     = (int*)take((size_t)PP * 128 * sizeof(int));
    int*   bukbase  = (int*)take((size_t)PP * 128 * sizeof(int));
    unsigned short* hb16   = (unsigned short*)take((size_t)N * INF_ * sizeof(unsigned short));
    unsigned short* Wpack  = (unsigned short*)take((size_t)PP * 8 * 4 * 64 * 8 * sizeof(unsigned short));
    unsigned short* W1pack = (unsigned short*)take((size_t)8 * 4 * 64 * 8 * sizeof(unsigned short));
    int    nblkM    = (N + 63) / 64;
    int    nblk4    = (N + 3) / 4;
    float* partials = (float*)take((size_t)PP * nblkM * sizeof(float));
    float* betap    = (float*)take(16);
    (void)ws_size; (void)n_in; (void)out_size;

    int total4 = N * INF_ / 4;
    dim3 gM(nblkM, PP);
    dim3 gNode(nblk4, PP);
    dim3 gA((E + ACH * 256 - 1) / (ACH * 256), PP);
    dim3 gB(nbuk, PP);

    kh_conv<<<(total4 + 255) / 256, 256, 0, stream>>>(h, hb16, gcur, total4);
    kw_pack<<<(PP * 2048 + 255) / 256, 256, 0, stream>>>(W, Wpack, PP, 0);
    kw_pack<<<(2048 + 255) / 256, 256, 0, stream>>>(W1, W1pack, 1, 1);
    k1_mfma<<<gM, 256, 0, stream>>>(hb16, Wpack, al, ar, featb, el, er, N);
    kA_bucket<<<gA, 256, 0, stream>>>(src, dst, gcur, barr, E);
    kscan_buckets<<<1, 128, 0, stream>>>(gcur, bukbase, offs, N, E, nbuk);
    kB_build<<<gB, 512, 0, stream>>>(barr, gcur, bukbase, offs, csr, N, E);
    k5_aggregate<<<gNode, 256, 0, stream>>>(featb, el, er, bias, offs, csr, z, zb16, N, E);
    k6_mfma<<<gM, 256, 0, stream>>>(zb16, W1pack, b1, W2, partials, N);
    k7_beta<<<1, 192, 0, stream>>>(partials, betap, nblkM, N);
    k8_combine<<<(int)(((size_t)N * FF / 4 + 255) / 256), 256, 0, stream>>>(z, betap, out, N);
}

// Round 3
// 307.716 us; speedup vs baseline: 1.0580x; 1.0580x over previous
//
#include <hip/hip_runtime.h>
#include <math.h>

#define PP 3
#define HH 4
#define DD 32
#define FF 128   // H*D
#define INF_ 128 // input feature dim
#define NEG_SLOPE 0.2f

#define BSHIFT 9          // bucket = dst >> 9  (512 nodes/bucket)
#define BW 512            // nodes per bucket
#define BCAP 10240        // max edges per bucket (mean ~8700 -> 17 sigma headroom)
#define ACH 8             // edge rounds per thread in kA (chunk = 2048 edges)

// Column permutation for featb/zb16 rows: word j holds cols (C(j), C(j)+16),
// C(j) = 32*(j>>4) + (j&15). Both cols of a word share head j>>4.
// k6's W1pack applies the matching k-permutation sigma.

typedef __bf16 bf16x8 __attribute__((ext_vector_type(8)));
typedef float f32x4 __attribute__((ext_vector_type(4)));

#define LO16F(u) __uint_as_float((u) << 16)
#define HI16F(u) __uint_as_float((u) & 0xFFFF0000u)

__device__ __forceinline__ unsigned int bf16pair(float x, float y) {
    unsigned int a = __float_as_uint(x);
    unsigned int b = __float_as_uint(y);
    a = (a + 0x7FFFu + ((a >> 16) & 1u)) >> 16;   // RNE round to bf16
    b = (b + 0x7FFFu + ((b >> 16) & 1u)) >> 16;
    return a | (b << 16);
}

// KH: h fp32 -> bf16 (once); also zeroes gcur (replaces a memset dispatch)
__global__ __launch_bounds__(256) void kh_conv(const float* __restrict__ h,
                                               unsigned short* __restrict__ hb16,
                                               int* __restrict__ gcur,
                                               int total4) {
    int i = blockIdx.x * 256 + threadIdx.x;
    if (i < PP * 128) gcur[i] = 0;
    if (i < total4) {
        float4 v = *(const float4*)&h[(size_t)i * 4];
        unsigned int lo = bf16pair(v.x, v.y);
        unsigned int hi = bf16pair(v.z, v.w);
        *(uint2*)&hb16[(size_t)i * 4] = make_uint2(lo, hi);
    }
}

// KW: pack nmat 128x128 fp32 matrices into B-fragment order for
// mfma_f32_16x16x32_bf16: B[k][n], n=lane&15, k=quad*8+j.
// perm!=0: apply sigma(k) = 32*((k>>1)>>4) + ((k>>1)&15) + 16*(k&1) to the
// k-row index (matches the permuted zb16 word layout).
__global__ __launch_bounds__(256) void kw_pack(const float* __restrict__ W,
                                               unsigned short* __restrict__ Wpack,
                                               int nmat, int perm) {
    int idx = blockIdx.x * 256 + threadIdx.x;
    if (idx >= nmat * 8 * 4 * 64) return;
    int lane = idx & 63;
    int ks = (idx >> 6) & 3;
    int nt = (idx >> 8) & 7;
    int m  = idx >> 11;
    int n  = nt * 16 + (lane & 15);
    int k0 = ks * 32 + (lane >> 4) * 8;
    const float* Wp = W + (size_t)m * INF_ * FF;
    float rowv[8];
#pragma unroll
    for (int i = 0; i < 8; ++i) {
        int k = k0 + i;
        if (perm) {
            int w = k >> 1;
            k = 32 * (w >> 4) + (w & 15) + 16 * (k & 1);
        }
        rowv[i] = Wp[(size_t)k * FF + n];
    }
    unsigned int u0 = bf16pair(rowv[0], rowv[1]);
    unsigned int u1 = bf16pair(rowv[2], rowv[3]);
    unsigned int u2 = bf16pair(rowv[4], rowv[5]);
    unsigned int u3 = bf16pair(rowv[6], rowv[7]);
    *(uint4*)&Wpack[(size_t)idx * 8] = make_uint4(u0, u1, u2, u3);
}

// K1: feat[p] = h @ W[p] via bf16 MFMA. 4 waves/block; wave = 16 rows x 128 cols.
// featb written in permuted word layout: word t16+16*np = pair(acc[2np], acc[2np+1])
// -> all-lane dense stores, no shuffles in the pack.
__global__ __launch_bounds__(256) void k1_mfma(const unsigned short* __restrict__ hb16,
                        const unsigned short* __restrict__ Wpack,
                        const float* __restrict__ al, const float* __restrict__ ar,
                        unsigned int* __restrict__ featb, float* __restrict__ el,
                        float* __restrict__ er, int N) {
    int l = threadIdx.x & 63;
    int wu = threadIdx.x >> 6;
    int p = blockIdx.y;
    int rowbase = blockIdx.x * 64 + wu * 16;
    if (rowbase >= N) return;
    int q = l >> 4;
    int t16 = l & 15;
    int arow = rowbase + t16; if (arow > N - 1) arow = N - 1;
    const unsigned short* hrow = hb16 + (size_t)arow * INF_ + q * 8;
    const unsigned short* wp = Wpack + (size_t)p * 8 * 4 * 64 * 8;

    f32x4 acc[8];
#pragma unroll
    for (int i = 0; i < 8; ++i) acc[i] = (f32x4){0.f, 0.f, 0.f, 0.f};

#pragma unroll
    for (int ks = 0; ks < 4; ++ks) {
        bf16x8 av = *(const bf16x8*)&hrow[ks * 32];
#pragma unroll
        for (int nt = 0; nt < 8; ++nt) {
            bf16x8 bv = *(const bf16x8*)&wp[(((size_t)nt * 4 + ks) * 64 + l) * 8];
            acc[nt] = __builtin_amdgcn_mfma_f32_16x16x32_bf16(av, bv, acc[nt], 0, 0, 0);
        }
    }

    float alv[8], arv[8];
#pragma unroll
    for (int nt = 0; nt < 8; ++nt) {
        int cc = (nt & 1) * 16 + t16;
        alv[nt] = al[((size_t)p * HH + (nt >> 1)) * DD + cc];
        arv[nt] = ar[((size_t)p * HH + (nt >> 1)) * DD + cc];
    }
    float elp[4][4], erp[4][4];
#pragma unroll
    for (int r = 0; r < 4; ++r)
#pragma unroll
        for (int hd = 0; hd < 4; ++hd) { elp[r][hd] = 0.f; erp[r][hd] = 0.f; }
#pragma unroll
    for (int nt = 0; nt < 8; ++nt)
#pragma unroll
        for (int r = 0; r < 4; ++r) {
            elp[r][nt >> 1] = fmaf(acc[nt][r], alv[nt], elp[r][nt >> 1]);
            erp[r][nt >> 1] = fmaf(acc[nt][r], arv[nt], erp[r][nt >> 1]);
        }
#pragma unroll
    for (int r = 0; r < 4; ++r)
#pragma unroll
        for (int hd = 0; hd < 4; ++hd) {
#pragma unroll
            for (int off = 8; off >= 1; off >>= 1) {
                elp[r][hd] += __shfl_xor(elp[r][hd], off);
                erp[r][hd] += __shfl_xor(erp[r][hd], off);
            }
        }

#pragma unroll
    for (int r = 0; r < 4; ++r) {
        int row = rowbase + q * 4 + r;
        bool vr = row < N;
        if (vr) {
            unsigned int* frow = featb + ((size_t)p * N + row) * 64;
#pragma unroll
            for (int np = 0; np < 4; ++np)
                frow[t16 + 16 * np] = bf16pair(acc[2 * np][r], acc[2 * np + 1][r]);
            if (t16 == 0) {
#pragma unroll
                for (int hd = 0; hd < 4; ++hd) {
                    el[((size_t)p * N + row) * HH + hd] = elp[r][hd];
                    er[((size_t)p * N + row) * HH + hd] = erp[r][hd];
                }
            }
        }
    }
}

// KA: bucket-partition edges by dst>>9. Per 2048-edge block: LDS histogram,
// one global atomicAdd per bucket reserves a dense run, edges written packed
// (src<<9 | dst&511) 4B each.
__global__ __launch_bounds__(256) void kA_bucket(const int* __restrict__ src,
        const int* __restrict__ dst, int* __restrict__ gcur,
        unsigned int* __restrict__ barr, int E) {
    __shared__ int cnt[128];
    __shared__ int gbase[128];
    int p = blockIdx.y;
    int t = threadIdx.x;
    int base = blockIdx.x * (ACH * 256);
    const int* sp = src + (size_t)p * E;
    const int* dp = dst + (size_t)p * E;
    if (t < 128) cnt[t] = 0;
    __syncthreads();
    int sv[ACH], dv[ACH], rv[ACH];
    bool val[ACH];
#pragma unroll
    for (int j = 0; j < ACH; ++j) {
        int idx = base + j * 256 + t;
        val[j] = idx < E;
        int ci = val[j] ? idx : (E - 1);
        dv[j] = dp[ci];
        sv[j] = sp[ci];
    }
#pragma unroll
    for (int j = 0; j < ACH; ++j)
        rv[j] = val[j] ? atomicAdd(&cnt[dv[j] >> BSHIFT], 1) : 0;
    __syncthreads();
    if (t < 128) gbase[t] = atomicAdd(&gcur[p * 128 + t], cnt[t]);
    __syncthreads();
#pragma unroll
    for (int j = 0; j < ACH; ++j) {
        if (val[j]) {
            int b = dv[j] >> BSHIFT;
            int posn = gbase[b] + rv[j];
            if (posn >= BCAP) posn = BCAP - 1;
            barr[(size_t)(p * 128 + b) * BCAP + posn] =
                ((unsigned int)sv[j] << BSHIFT) | (unsigned int)(dv[j] & (BW - 1));
        }
    }
}

// KScan: exclusive scan of per-bucket counts -> bucket bases; offs[N]=E.
__global__ __launch_bounds__(128) void kscan_buckets(const int* __restrict__ gcur,
        int* __restrict__ bukbase, int* __restrict__ offs, int N, int E, int nbuk) {
    __shared__ int sc[128];
    int t = threadIdx.x;
    for (int p = 0; p < PP; ++p) {
        int v = (t < nbuk) ? gcur[p * 128 + t] : 0;
        sc[t] = v;
        __syncthreads();
        for (int off = 1; off < 128; off <<= 1) {
            int u = (t >= off) ? sc[t - off] : 0;
            __syncthreads();
            sc[t] += u;
            __syncthreads();
        }
        if (t < nbuk) bukbase[p * 128 + t] = sc[t] - v;
        if (t == 0) offs[(size_t)p * (N + 1) + N] = E;
        __syncthreads();
    }
}

// KB: per-(bucket,path) CSR build entirely in LDS.
__global__ __launch_bounds__(512) void kB_build(const unsigned int* __restrict__ barr,
        const int* __restrict__ gcur, const int* __restrict__ bukbase,
        int* __restrict__ offs, int* __restrict__ csr, int N, int E) {
    __shared__ int cnt[BW];
    __shared__ int curs[BW];
    __shared__ int slice[BCAP];   // 40 KB
    int p = blockIdx.y, b = blockIdx.x;
    int t = threadIdx.x;
    int n0 = b << BSHIFT;
    int ncnt = N - n0; if (ncnt > BW) ncnt = BW;
    int ecnt = gcur[p * 128 + b]; if (ecnt > BCAP) ecnt = BCAP;
    int gb = bukbase[p * 128 + b];
    const unsigned int* ba = barr + (size_t)(p * 128 + b) * BCAP;
    cnt[t] = 0;
    __syncthreads();
    for (int i = t; i < ecnt; i += BW)
        atomicAdd(&cnt[ba[i] & (BW - 1u)], 1);
    __syncthreads();
    int myc = (t < ncnt) ? cnt[t] : 0;
    slice[t] = myc;
    __syncthreads();
    for (int off = 1; off < BW; off <<= 1) {
        int v = (t >= off) ? slice[t - off] : 0;
        __syncthreads();
        slice[t] += v;
        __syncthreads();
    }
    int excl = slice[t] - myc;
    if (t < ncnt) {
        curs[t] = excl;
        offs[(size_t)p * (N + 1) + n0 + t] = gb + excl;
    }
    __syncthreads();
    for (int i = t; i < ecnt; i += BW) {
        unsigned int v = ba[i];
        int pos = atomicAdd(&curs[v & (BW - 1u)], 1);
        slice[pos] = (int)(v >> BSHIFT);
    }
    __syncthreads();
    for (int i = t; i < ecnt; i += BW)
        csr[(size_t)p * E + gb + i] = slice[i];
}

// K5: per-(node,path) single-pass softmax aggregation, NODE-PER-QUARTER scheme.
// Each 16-lane quarter q owns node n = blk*16 + wave*4 + q. Per edge, the
// quarter's 16 lanes gather the full 256B featb row (one dwordx4 each); one
// wave load-instr serves 4 edges (one per quarter), and 8 edges per quarter
// are unrolled per group -> 8 independent dwordx4 loads in flight per wave
// (restores the MLP the round-2 version lost, keeps the x4 instr density).
// No cross-quarter reduction: lane (q,t) owns words 4t..4t+3 of its node,
// sumw accumulates per-head locally, epilogue stores are 2x float4 + 1x uint4.
// Degree divergence across quarters handled by per-quarter cnt branches
// (exec-masked); padded edges gather row 0 (L2-hot) with weight 0.
// wbuf quarter stride 68 floats -> bank-conflict-free weight reads.
__global__ __launch_bounds__(256) void k5_aggregate(const unsigned int* __restrict__ featb,
                             const float* __restrict__ el, const float* __restrict__ er,
                             const float* __restrict__ bias,
                             const int* __restrict__ offs, const int* __restrict__ csr,
                             float* __restrict__ z, unsigned int* __restrict__ zb16,
                             int N, int E) {
    __shared__ float wbuf[4][4][68];   // [wave][quarter][16 edges x 4 heads + pad]
    int w = threadIdx.x >> 6, l = threadIdx.x & 63;
    int q = l >> 4;          // quarter: owns its own node
    int t = l & 15;          // lane within quarter: owns words 4t..4t+3
    int hd = t >> 2;         // head of those words
    int p = blockIdx.y;
    int n = blockIdx.x * 16 + w * 4 + q;
    int nc = n < N ? n : N - 1;
    const float* elp = el + (size_t)p * N * HH;
    const float* erp = er + (size_t)p * N * HH;
    float4 rv = *(const float4*)&erp[(size_t)nc * HH];
    const int* op = offs + (size_t)p * (N + 1) + nc;
    int j0 = op[0];
    int j1 = op[1];
    if (n >= N) j1 = j0;
    const int* cs = csr + (size_t)p * E;
    const char* fpb = (const char*)(featb + (size_t)p * N * 64);

    int d = j1 - j0;
    int dmax = d;
    dmax = max(dmax, __shfl_xor(dmax, 16));
    dmax = max(dmax, __shfl_xor(dmax, 32));
    int nchunk = (dmax + 15) >> 4;

    float a00 = 0.f, a01 = 0.f, a10 = 0.f, a11 = 0.f;
    float a20 = 0.f, a21 = 0.f, a30 = 0.f, a31 = 0.f;
    float sumw = 0.f;
    unsigned tb = (unsigned)t << 4;
    float* wq = &wbuf[w][q][0];
    int qb = q << 4;

#define ACC1(vv, ww) \
    a00 = fmaf(ww, LO16F(vv.x), a00); a01 = fmaf(ww, HI16F(vv.x), a01); \
    a10 = fmaf(ww, LO16F(vv.y), a10); a11 = fmaf(ww, HI16F(vv.y), a11); \
    a20 = fmaf(ww, LO16F(vv.z), a20); a21 = fmaf(ww, HI16F(vv.z), a21); \
    a30 = fmaf(ww, LO16F(vv.w), a30); a31 = fmaf(ww, HI16F(vv.w), a31); \
    sumw += ww;

#define GROUP8(E0) { \
    unsigned o0 = __shfl(boff, qb + (E0 + 0)) + tb; \
    unsigned o1 = __shfl(boff, qb + (E0 + 1)) + tb; \
    unsigned o2 = __shfl(boff, qb + (E0 + 2)) + tb; \
    unsigned o3 = __shfl(boff, qb + (E0 + 3)) + tb; \
    unsigned o4 = __shfl(boff, qb + (E0 + 4)) + tb; \
    unsigned o5 = __shfl(boff, qb + (E0 + 5)) + tb; \
    unsigned o6 = __shfl(boff, qb + (E0 + 6)) + tb; \
    unsigned o7 = __shfl(boff, qb + (E0 + 7)) + tb; \
    uint4 v0 = *(const uint4*)(fpb + o0); \
    uint4 v1 = *(const uint4*)(fpb + o1); \
    uint4 v2 = *(const uint4*)(fpb + o2); \
    uint4 v3 = *(const uint4*)(fpb + o3); \
    uint4 v4 = *(const uint4*)(fpb + o4); \
    uint4 v5 = *(const uint4*)(fpb + o5); \
    uint4 v6 = *(const uint4*)(fpb + o6); \
    uint4 v7 = *(const uint4*)(fpb + o7); \
    float w0 = wq[(E0 + 0) * 4 + hd]; \
    float w1 = wq[(E0 + 1) * 4 + hd]; \
    float w2 = wq[(E0 + 2) * 4 + hd]; \
    float w3 = wq[(E0 + 3) * 4 + hd]; \
    float w4 = wq[(E0 + 4) * 4 + hd]; \
    float w5 = wq[(E0 + 5) * 4 + hd]; \
    float w6 = wq[(E0 + 6) * 4 + hd]; \
    float w7 = wq[(E0 + 7) * 4 + hd]; \
    ACC1(v0, w0) ACC1(v1, w1) ACC1(v2, w2) ACC1(v3, w3) \
    ACC1(v4, w4) ACC1(v5, w5) ACC1(v6, w6) ACC1(v7, w7) }

    for (int c = 0; c < nchunk; ++c) {
        int eb = j0 + (c << 4);
        int cnt = j1 - eb;              // uniform within quarter
        int idx = eb + t;
        bool vald = idx < j1;
        int mysn = (vald && cnt > 0) ? cs[idx] : 0;
        unsigned boff = (unsigned)mysn << 8;
        if (cnt > 0) {
            float4 ev = *(const float4*)((const char*)elp + ((unsigned)mysn << 4));
            float4 wv;
            float e;
            e = ev.x + rv.x; e = fmaxf(e, NEG_SLOPE * e); wv.x = vald ? __expf(e) : 0.f;
            e = ev.y + rv.y; e = fmaxf(e, NEG_SLOPE * e); wv.y = vald ? __expf(e) : 0.f;
            e = ev.z + rv.z; e = fmaxf(e, NEG_SLOPE * e); wv.z = vald ? __expf(e) : 0.f;
            e = ev.w + rv.w; e = fmaxf(e, NEG_SLOPE * e); wv.w = vald ? __expf(e) : 0.f;
            *(float4*)&wq[t * 4] = wv;
            GROUP8(0)
        }
        if (cnt > 8) {
            GROUP8(8)
        }
    }
#undef GROUP8
#undef ACC1

    if (n < N) {
        float inv = 1.f / sumw;
        int ca0 = 32 * hd + ((4 * t) & 15);   // first of 4 consecutive cols
        const float* bp = bias + p * FF + ca0;
        float4 blo = *(const float4*)bp;
        float4 bhi = *(const float4*)(bp + 16);
        float z00 = fmaf(a00, inv, blo.x);
        float z10 = fmaf(a10, inv, blo.y);
        float z20 = fmaf(a20, inv, blo.z);
        float z30 = fmaf(a30, inv, blo.w);
        float z01 = fmaf(a01, inv, bhi.x);
        float z11 = fmaf(a11, inv, bhi.y);
        float z21 = fmaf(a21, inv, bhi.z);
        float z31 = fmaf(a31, inv, bhi.w);
        z00 = z00 > 0.f ? z00 : __expf(z00) - 1.f;
        z10 = z10 > 0.f ? z10 : __expf(z10) - 1.f;
        z20 = z20 > 0.f ? z20 : __expf(z20) - 1.f;
        z30 = z30 > 0.f ? z30 : __expf(z30) - 1.f;
        z01 = z01 > 0.f ? z01 : __expf(z01) - 1.f;
        z11 = z11 > 0.f ? z11 : __expf(z11) - 1.f;
        z21 = z21 > 0.f ? z21 : __expf(z21) - 1.f;
        z31 = z31 > 0.f ? z31 : __expf(z31) - 1.f;
        size_t zb = ((size_t)p * N + n) * FF;
        float4 lo = make_float4(z00, z10, z20, z30);
        float4 hi = make_float4(z01, z11, z21, z31);
        *(float4*)&z[zb + ca0] = lo;
        *(float4*)&z[zb + ca0 + 16] = hi;
        uint4 pk = make_uint4(bf16pair(z00, z01), bf16pair(z10, z11),
                              bf16pair(z20, z21), bf16pair(z30, z31));
        *(uint4*)&zb16[((size_t)p * N + n) * 64 + 4 * t] = pk;
    }
}

// K6: s[n,p] = tanh(z @ W1 + b1) @ W2 via bf16 MFMA (W1pack k-permuted to
// match zb16 word layout), summed per block.
__global__ __launch_bounds__(256) void k6_mfma(const unsigned int* __restrict__ zb16,
                        const unsigned short* __restrict__ W1pack,
                        const float* __restrict__ b1, const float* __restrict__ W2,
                        float* __restrict__ partials, int N) {
    __shared__ float wsum[4];
    int l = threadIdx.x & 63;
    int wu = threadIdx.x >> 6;
    int p = blockIdx.y;
    int rowbase = blockIdx.x * 64 + wu * 16;
    float ssum = 0.f;
    if (rowbase < N) {
        int q = l >> 4;
        int t16 = l & 15;
        int arow = rowbase + t16; if (arow > N - 1) arow = N - 1;
        const unsigned short* zrow =
            (const unsigned short*)(zb16 + ((size_t)p * N + arow) * 64) + q * 8;

        f32x4 acc[8];
#pragma unroll
        for (int i = 0; i < 8; ++i) acc[i] = (f32x4){0.f, 0.f, 0.f, 0.f};
#pragma unroll
        for (int ks = 0; ks < 4; ++ks) {
            bf16x8 av = *(const bf16x8*)&zrow[ks * 32];
#pragma unroll
            for (int nt = 0; nt < 8; ++nt) {
                bf16x8 bv = *(const bf16x8*)&W1pack[(((size_t)nt * 4 + ks) * 64 + l) * 8];
                acc[nt] = __builtin_amdgcn_mfma_f32_16x16x32_bf16(av, bv, acc[nt], 0, 0, 0);
            }
        }
        float b1v[8], w2v[8];
#pragma unroll
        for (int nt = 0; nt < 8; ++nt) {
            int col = nt * 16 + t16;
            b1v[nt] = b1[col];
            w2v[nt] = W2[col];
        }
        float rowsum[4] = {0.f, 0.f, 0.f, 0.f};
#pragma unroll
        for (int nt = 0; nt < 8; ++nt)
#pragma unroll
            for (int r = 0; r < 4; ++r) {
                float a = acc[nt][r] + b1v[nt];
                float e = __expf(2.f * a);
                float t = 1.f - 2.f * __builtin_amdgcn_rcpf(e + 1.f);
                rowsum[r] = fmaf(t, w2v[nt], rowsum[r]);
            }
#pragma unroll
        for (int r = 0; r < 4; ++r) {
            int row = rowbase + q * 4 + r;
            ssum += (row < N) ? rowsum[r] : 0.f;
        }
#pragma unroll
        for (int off = 32; off >= 1; off >>= 1) ssum += __shfl_xor(ssum, off);
    }
    if (l == 0) wsum[wu] = ssum;
    __syncthreads();
    if (threadIdx.x == 0)
        partials[(size_t)p * gridDim.x + blockIdx.x] = wsum[0] + wsum[1] + wsum[2] + wsum[3];
}

// K7: reduce partials -> w[p] mean -> beta softmax. one block, 3 waves.
__global__ void k7_beta(const float* __restrict__ partials, float* __restrict__ beta,
                        int nblk, int N) {
    __shared__ float wl[3];
    int p = threadIdx.x >> 6, l = threadIdx.x & 63;
    float s = 0.f;
    for (int i = l; i < nblk; i += 64) s += partials[(size_t)p * nblk + i];
    for (int off = 32; off >= 1; off >>= 1) s += __shfl_xor(s, off);
    if (l == 0) wl[p] = s / (float)N;
    __syncthreads();
    if (threadIdx.x == 0) {
        float m = fmaxf(wl[0], fmaxf(wl[1], wl[2]));
        float e0 = __expf(wl[0] - m), e1 = __expf(wl[1] - m), e2 = __expf(wl[2] - m);
        float inv = 1.f / (e0 + e1 + e2);
        beta[0] = e0 * inv; beta[1] = e1 * inv; beta[2] = e2 * inv;
    }
}

// K8: out[n,:] = sum_p beta[p] * z[p][n,:]  (fp32, float4 vectorized)
__global__ void k8_combine(const float* __restrict__ z, const float* __restrict__ beta,
                           float* __restrict__ out, int N) {
    size_t i = (size_t)blockIdx.x * 256 + threadIdx.x;
    size_t tot4 = (size_t)N * FF / 4;
    if (i < tot4) {
        float b0 = beta[0], b1 = beta[1], b2 = beta[2];
        const float4* z4 = (const float4*)z;
        float4 a = z4[i], b = z4[tot4 + i], c = z4[2 * tot4 + i];
        float4 o;
        o.x = b0 * a.x + b1 * b.x + b2 * c.x;
        o.y = b0 * a.y + b1 * b.y + b2 * c.y;
        o.z = b0 * a.z + b1 * b.z + b2 * c.z;
        o.w = b0 * a.w + b1 * b.w + b2 * c.w;
        ((float4*)out)[i] = o;
    }
}

extern "C" void kernel_launch(void* const* d_in, const int* in_sizes, int n_in,
                              void* d_out, int out_size, void* d_ws, size_t ws_size,
                              hipStream_t stream) {
    const float* h    = (const float*)d_in[0];
    const float* W    = (const float*)d_in[1];
    const float* al   = (const float*)d_in[2];
    const float* ar   = (const float*)d_in[3];
    const float* bias = (const float*)d_in[4];
    const float* W1   = (const float*)d_in[5];
    const float* b1   = (const float*)d_in[6];
    const float* W2   = (const float*)d_in[7];
    const int*   src  = (const int*)d_in[8];
    const int*   dst  = (const int*)d_in[9];
    float* out = (float*)d_out;

    int N = in_sizes[0] / INF_;
    int E = in_sizes[8] / PP;
    int nbuk = (N + BW - 1) >> BSHIFT;

    char* ws = (char*)d_ws;
    size_t off = 0;
    auto take = [&](size_t bytes) -> void* {
        off = (off + 255) & ~(size_t)255;
        void* ptr = ws + off;
        off += bytes;
        return ptr;
    };
    unsigned int* featb = (unsigned int*)take((size_t)PP * N * 64 * sizeof(unsigned int));
    float* z        = (float*)take((size_t)PP * N * FF * sizeof(float));
    unsigned int* zb16 = (unsigned int*)take((size_t)PP * N * 64 * sizeof(unsigned int));
    float* el       = (float*)take((size_t)PP * N * HH * sizeof(float));
    float* er       = (float*)take((size_t)PP * N * HH * sizeof(float));
    int*   offs     = (int*)take((size_t)PP * (N + 1) * sizeof(int));
    int*   csr      = (int*)take((size_t)PP * E * sizeof(int));
    unsigned int* barr = (unsigned int*)take((size_t)PP * 128 * BCAP * sizeof(unsigned int));
    int*   gcur     = (int*)take((size_t)PP * 128 * sizeof(int));
    int*   bukbase  = (int*)take((size_t)PP * 128 * sizeof(int));
    unsigned short* hb16   = (unsigned short*)take((size_t)N * INF_ * sizeof(unsigned short));
    unsigned short* Wpack  = (unsigned short*)take((size_t)PP * 8 * 4 * 64 * 8 * sizeof(unsigned short));
    unsigned short* W1pack = (unsigned short*)take((size_t)8 * 4 * 64 * 8 * sizeof(unsigned short));
    int    nblkM    = (N + 63) / 64;
    int    nblk16   = (N + 15) / 16;
    float* partials = (float*)take((size_t)PP * nblkM * sizeof(float));
    float* betap    = (float*)take(16);
    (void)ws_size; (void)n_in; (void)out_size;

    int total4 = N * INF_ / 4;
    dim3 gM(nblkM, PP);
    dim3 gNode(nblk16, PP);
    dim3 gA((E + ACH * 256 - 1) / (ACH * 256), PP);
    dim3 gB(nbuk, PP);

    kh_conv<<<(total4 + 255) / 256, 256, 0, stream>>>(h, hb16, gcur, total4);
    kw_pack<<<(PP * 2048 + 255) / 256, 256, 0, stream>>>(W, Wpack, PP, 0);
    kw_pack<<<(2048 + 255) / 256, 256, 0, stream>>>(W1, W1pack, 1, 1);
    k1_mfma<<<gM, 256, 0, stream>>>(hb16, Wpack, al, ar, featb, el, er, N);
    kA_bucket<<<gA, 256, 0, stream>>>(src, dst, gcur, barr, E);
    kscan_buckets<<<1, 128, 0, stream>>>(gcur, bukbase, offs, N, E, nbuk);
    kB_build<<<gB, 512, 0, stream>>>(barr, gcur, bukbase, offs, csr, N, E);
    k5_aggregate<<<gNode, 256, 0, stream>>>(featb, el, er, bias, offs, csr, z, zb16, N, E);
    k6_mfma<<<gM, 256, 0, stream>>>(zb16, W1pack, b1, W2, partials, N);
    k7_beta<<<1, 192, 0, stream>>>(partials, betap, nblkM, N);
    k8_combine<<<(int)(((size_t)N * FF / 4 + 255) / 256), 256, 0, stream>>>(z, betap, out, N);
}

// Round 5
// 304.002 us; speedup vs baseline: 1.0709x; 1.0122x over previous
//
#include <hip/hip_runtime.h>
#include <math.h>

#define PP 3
#define HH 4
#define DD 32
#define FF 128   // H*D
#define INF_ 128 // input feature dim
#define NEG_SLOPE 0.2f

#define BSHIFT 9          // bucket = dst >> 9  (512 nodes/bucket)
#define BW 512            // nodes per bucket
#define BCAP 10240        // max edges per bucket (mean ~8700 -> 17 sigma headroom)
#define ACH 8             // edge rounds per thread in kA (chunk = 2048 edges)

// Column permutation for featb/zb16 rows: word j holds cols (C(j), C(j)+16),
// C(j) = 32*(j>>4) + (j&15). Both cols of a word share head j>>4.
// k6's W1pack applies the matching k-permutation sigma.

typedef __bf16 bf16x8 __attribute__((ext_vector_type(8)));
typedef float f32x4 __attribute__((ext_vector_type(4)));

#define LO16F(u) __uint_as_float((u) << 16)
#define HI16F(u) __uint_as_float((u) & 0xFFFF0000u)

__device__ __forceinline__ unsigned int bf16pair(float x, float y) {
    unsigned int a = __float_as_uint(x);
    unsigned int b = __float_as_uint(y);
    a = (a + 0x7FFFu + ((a >> 16) & 1u)) >> 16;   // RNE round to bf16
    b = (b + 0x7FFFu + ((b >> 16) & 1u)) >> 16;
    return a | (b << 16);
}

// pack one 128x128 fp32 matrix row-group into B-fragment order for
// mfma_f32_16x16x32_bf16: B[k][n], n=lane&15, k=quad*8+j.
// perm!=0: apply sigma(k) = 32*((k>>1)>>4) + ((k>>1)&15) + 16*(k&1)
// (matches the permuted zb16 word layout).
__device__ __forceinline__ void pack_one(const float* __restrict__ Wbase,
                                         unsigned short* __restrict__ Wdst,
                                         int idx, int perm) {
    int lane = idx & 63;
    int ks = (idx >> 6) & 3;
    int nt = (idx >> 8) & 7;
    int m  = idx >> 11;
    int n  = nt * 16 + (lane & 15);
    int k0 = ks * 32 + (lane >> 4) * 8;
    const float* Wp = Wbase + (size_t)m * INF_ * FF;
    float rowv[8];
#pragma unroll
    for (int i = 0; i < 8; ++i) {
        int k = k0 + i;
        if (perm) {
            int w = k >> 1;
            k = 32 * (w >> 4) + (w & 15) + 16 * (k & 1);
        }
        rowv[i] = Wp[(size_t)k * FF + n];
    }
    unsigned int u0 = bf16pair(rowv[0], rowv[1]);
    unsigned int u1 = bf16pair(rowv[2], rowv[3]);
    unsigned int u2 = bf16pair(rowv[4], rowv[5]);
    unsigned int u3 = bf16pair(rowv[6], rowv[7]);
    *(uint4*)&Wdst[(size_t)idx * 8] = make_uint4(u0, u1, u2, u3);
}

// MEGA0: kh_conv (h fp32->bf16 + gcur zero) | kw_pack(W, perm=0) |
// kw_pack(W1, perm=1) -- all independent, fused to cut 2 dispatch boundaries.
__global__ __launch_bounds__(256) void mega0(const float* __restrict__ h,
                                             unsigned short* __restrict__ hb16,
                                             int* __restrict__ gcur, int total4,
                                             int khblocks,
                                             const float* __restrict__ W,
                                             unsigned short* __restrict__ Wpack,
                                             const float* __restrict__ W1,
                                             unsigned short* __restrict__ W1pack) {
    int bx = blockIdx.x;
    if (bx < khblocks) {
        int i = bx * 256 + threadIdx.x;
        if (i < PP * 128) gcur[i] = 0;
        if (i < total4) {
            float4 v = *(const float4*)&h[(size_t)i * 4];
            unsigned int lo = bf16pair(v.x, v.y);
            unsigned int hi = bf16pair(v.z, v.w);
            *(uint2*)&hb16[(size_t)i * 4] = make_uint2(lo, hi);
        }
    } else {
        int idx = (bx - khblocks) * 256 + threadIdx.x;
        if (idx < PP * 2048) {
            pack_one(W, Wpack, idx, 0);
        } else if (idx < PP * 2048 + 2048) {
            pack_one(W1, W1pack, idx - PP * 2048, 1);
        }
    }
}

// MEGA1: k1_mfma | kA_bucket -- independent stages fused into one dispatch.
// k1: feat[p] = h @ W[p] via bf16 MFMA. 4 waves/block; wave = 16 rows x 128 cols.
// featb written in permuted word layout: word t16+16*np = pair(acc[2np], acc[2np+1]).
// kA: bucket-partition edges by dst>>9; per 2048-edge block: LDS histogram,
// one global atomicAdd per bucket reserves a dense run, edges packed 4B.
__global__ __launch_bounds__(256) void mega1(const unsigned short* __restrict__ hb16,
                        const unsigned short* __restrict__ Wpack,
                        const float* __restrict__ al, const float* __restrict__ ar,
                        unsigned int* __restrict__ featb, float* __restrict__ el,
                        float* __restrict__ er, int N, int nblk1,
                        const int* __restrict__ src, const int* __restrict__ dst,
                        int* __restrict__ gcur, unsigned int* __restrict__ barr, int E) {
    __shared__ int cnt[128];
    __shared__ int gbase[128];
    int p = blockIdx.y;
    if ((int)blockIdx.x < nblk1) {
        // ---- k1 branch ----
        int l = threadIdx.x & 63;
        int wu = threadIdx.x >> 6;
        int rowbase = blockIdx.x * 64 + wu * 16;
        if (rowbase >= N) return;
        int q = l >> 4;
        int t16 = l & 15;
        int arow = rowbase + t16; if (arow > N - 1) arow = N - 1;
        const unsigned short* hrow = hb16 + (size_t)arow * INF_ + q * 8;
        const unsigned short* wp = Wpack + (size_t)p * 8 * 4 * 64 * 8;

        f32x4 acc[8];
#pragma unroll
        for (int i = 0; i < 8; ++i) acc[i] = (f32x4){0.f, 0.f, 0.f, 0.f};

#pragma unroll
        for (int ks = 0; ks < 4; ++ks) {
            bf16x8 av = *(const bf16x8*)&hrow[ks * 32];
#pragma unroll
            for (int nt = 0; nt < 8; ++nt) {
                bf16x8 bv = *(const bf16x8*)&wp[(((size_t)nt * 4 + ks) * 64 + l) * 8];
                acc[nt] = __builtin_amdgcn_mfma_f32_16x16x32_bf16(av, bv, acc[nt], 0, 0, 0);
            }
        }

        float alv[8], arv[8];
#pragma unroll
        for (int nt = 0; nt < 8; ++nt) {
            int cc = (nt & 1) * 16 + t16;
            alv[nt] = al[((size_t)p * HH + (nt >> 1)) * DD + cc];
            arv[nt] = ar[((size_t)p * HH + (nt >> 1)) * DD + cc];
        }
        float elp[4][4], erp[4][4];
#pragma unroll
        for (int r = 0; r < 4; ++r)
#pragma unroll
            for (int hd = 0; hd < 4; ++hd) { elp[r][hd] = 0.f; erp[r][hd] = 0.f; }
#pragma unroll
        for (int nt = 0; nt < 8; ++nt)
#pragma unroll
            for (int r = 0; r < 4; ++r) {
                elp[r][nt >> 1] = fmaf(acc[nt][r], alv[nt], elp[r][nt >> 1]);
                erp[r][nt >> 1] = fmaf(acc[nt][r], arv[nt], erp[r][nt >> 1]);
            }
#pragma unroll
        for (int r = 0; r < 4; ++r)
#pragma unroll
            for (int hd = 0; hd < 4; ++hd) {
#pragma unroll
                for (int off = 8; off >= 1; off >>= 1) {
                    elp[r][hd] += __shfl_xor(elp[r][hd], off);
                    erp[r][hd] += __shfl_xor(erp[r][hd], off);
                }
            }

#pragma unroll
        for (int r = 0; r < 4; ++r) {
            int row = rowbase + q * 4 + r;
            bool vr = row < N;
            if (vr) {
                unsigned int* frow = featb + ((size_t)p * N + row) * 64;
#pragma unroll
                for (int np = 0; np < 4; ++np)
                    frow[t16 + 16 * np] = bf16pair(acc[2 * np][r], acc[2 * np + 1][r]);
                if (t16 == 0) {
#pragma unroll
                    for (int hd = 0; hd < 4; ++hd) {
                        el[((size_t)p * N + row) * HH + hd] = elp[r][hd];
                        er[((size_t)p * N + row) * HH + hd] = erp[r][hd];
                    }
                }
            }
        }
    } else {
        // ---- kA branch ----
        int t = threadIdx.x;
        int base = (blockIdx.x - nblk1) * (ACH * 256);
        const int* sp = src + (size_t)p * E;
        const int* dp = dst + (size_t)p * E;
        if (t < 128) cnt[t] = 0;
        __syncthreads();
        int sv[ACH], dv[ACH], rv[ACH];
        bool val[ACH];
#pragma unroll
        for (int j = 0; j < ACH; ++j) {
            int idx = base + j * 256 + t;
            val[j] = idx < E;
            int ci = val[j] ? idx : (E - 1);
            dv[j] = dp[ci];
            sv[j] = sp[ci];
        }
#pragma unroll
        for (int j = 0; j < ACH; ++j)
            rv[j] = val[j] ? atomicAdd(&cnt[dv[j] >> BSHIFT], 1) : 0;
        __syncthreads();
        if (t < 128) gbase[t] = atomicAdd(&gcur[p * 128 + t], cnt[t]);
        __syncthreads();
#pragma unroll
        for (int j = 0; j < ACH; ++j) {
            if (val[j]) {
                int b = dv[j] >> BSHIFT;
                int posn = gbase[b] + rv[j];
                if (posn >= BCAP) posn = BCAP - 1;
                barr[(size_t)(p * 128 + b) * BCAP + posn] =
                    ((unsigned int)sv[j] << BSHIFT) | (unsigned int)(dv[j] & (BW - 1));
            }
        }
    }
}

// KB: per-(bucket,path) CSR build entirely in LDS. Now also derives its own
// bucket base via an inline 128-wide scan of gcur (absorbs the old kscan
// kernel: 512B read + 7 LDS rounds per block).
__global__ __launch_bounds__(512) void kB_build(const unsigned int* __restrict__ barr,
        const int* __restrict__ gcur,
        int* __restrict__ offs, int* __restrict__ csr, int N, int E, int nbuk) {
    __shared__ int cnt[BW];
    __shared__ int curs[BW];
    __shared__ int slice[BCAP];   // 40 KB
    int p = blockIdx.y, b = blockIdx.x;
    int t = threadIdx.x;
    // inline inclusive scan of per-bucket counts -> this block's base gb
    if (t < 128) cnt[t] = (t < nbuk) ? gcur[p * 128 + t] : 0;
    __syncthreads();
    for (int off = 1; off < 128; off <<= 1) {
        int u = (t < 128 && t >= off) ? cnt[t - off] : 0;
        __syncthreads();
        if (t < 128) cnt[t] += u;
        __syncthreads();
    }
    int gb = (b == 0) ? 0 : cnt[b - 1];
    if (b == nbuk - 1 && t == 0) offs[(size_t)p * (N + 1) + N] = E;
    __syncthreads();

    int n0 = b << BSHIFT;
    int ncnt = N - n0; if (ncnt > BW) ncnt = BW;
    int ecnt = gcur[p * 128 + b]; if (ecnt > BCAP) ecnt = BCAP;
    const unsigned int* ba = barr + (size_t)(p * 128 + b) * BCAP;
    cnt[t] = 0;
    __syncthreads();
    for (int i = t; i < ecnt; i += BW)
        atomicAdd(&cnt[ba[i] & (BW - 1u)], 1);
    __syncthreads();
    int myc = (t < ncnt) ? cnt[t] : 0;
    slice[t] = myc;
    __syncthreads();
    for (int off = 1; off < BW; off <<= 1) {
        int v = (t >= off) ? slice[t - off] : 0;
        __syncthreads();
        slice[t] += v;
        __syncthreads();
    }
    int excl = slice[t] - myc;
    if (t < ncnt) {
        curs[t] = excl;
        offs[(size_t)p * (N + 1) + n0 + t] = gb + excl;
    }
    __syncthreads();
    for (int i = t; i < ecnt; i += BW) {
        unsigned int v = ba[i];
        int pos = atomicAdd(&curs[v & (BW - 1u)], 1);
        slice[pos] = (int)(v >> BSHIFT);
    }
    __syncthreads();
    for (int i = t; i < ecnt; i += BW)
        csr[(size_t)p * E + gb + i] = slice[i];
}

// K5: per-(node,path) single-pass softmax aggregation, NODE-PER-QUARTER scheme.
// Each 16-lane quarter q owns node n = blk*16 + wave*4 + q. Per edge, the
// quarter's 16 lanes gather the full 256B featb row (one dwordx4 each); one
// wave load-instr serves 4 edges (one per quarter), 8 edges per quarter
// unrolled per group -> 8 independent dwordx4 loads in flight per wave.
// Counters say this is near the random-256B-gather HBM ceiling (~4.1 TB/s).
__global__ __launch_bounds__(256) void k5_aggregate(const unsigned int* __restrict__ featb,
                             const float* __restrict__ el, const float* __restrict__ er,
                             const float* __restrict__ bias,
                             const int* __restrict__ offs, const int* __restrict__ csr,
                             float* __restrict__ z, unsigned int* __restrict__ zb16,
                             int N, int E) {
    __shared__ float wbuf[4][4][68];   // [wave][quarter][16 edges x 4 heads + pad]
    int w = threadIdx.x >> 6, l = threadIdx.x & 63;
    int q = l >> 4;          // quarter: owns its own node
    int t = l & 15;          // lane within quarter: owns words 4t..4t+3
    int hd = t >> 2;         // head of those words
    int p = blockIdx.y;
    int n = blockIdx.x * 16 + w * 4 + q;
    int nc = n < N ? n : N - 1;
    const float* elp = el + (size_t)p * N * HH;
    const float* erp = er + (size_t)p * N * HH;
    float4 rv = *(const float4*)&erp[(size_t)nc * HH];
    const int* op = offs + (size_t)p * (N + 1) + nc;
    int j0 = op[0];
    int j1 = op[1];
    if (n >= N) j1 = j0;
    const int* cs = csr + (size_t)p * E;
    const char* fpb = (const char*)(featb + (size_t)p * N * 64);

    int d = j1 - j0;
    int dmax = d;
    dmax = max(dmax, __shfl_xor(dmax, 16));
    dmax = max(dmax, __shfl_xor(dmax, 32));
    int nchunk = (dmax + 15) >> 4;

    float a00 = 0.f, a01 = 0.f, a10 = 0.f, a11 = 0.f;
    float a20 = 0.f, a21 = 0.f, a30 = 0.f, a31 = 0.f;
    float sumw = 0.f;
    unsigned tb = (unsigned)t << 4;
    float* wq = &wbuf[w][q][0];
    int qb = q << 4;

#define ACC1(vv, ww) \
    a00 = fmaf(ww, LO16F(vv.x), a00); a01 = fmaf(ww, HI16F(vv.x), a01); \
    a10 = fmaf(ww, LO16F(vv.y), a10); a11 = fmaf(ww, HI16F(vv.y), a11); \
    a20 = fmaf(ww, LO16F(vv.z), a20); a21 = fmaf(ww, HI16F(vv.z), a21); \
    a30 = fmaf(ww, LO16F(vv.w), a30); a31 = fmaf(ww, HI16F(vv.w), a31); \
    sumw += ww;

#define GROUP8(E0) { \
    unsigned o0 = __shfl(boff, qb + (E0 + 0)) + tb; \
    unsigned o1 = __shfl(boff, qb + (E0 + 1)) + tb; \
    unsigned o2 = __shfl(boff, qb + (E0 + 2)) + tb; \
    unsigned o3 = __shfl(boff, qb + (E0 + 3)) + tb; \
    unsigned o4 = __shfl(boff, qb + (E0 + 4)) + tb; \
    unsigned o5 = __shfl(boff, qb + (E0 + 5)) + tb; \
    unsigned o6 = __shfl(boff, qb + (E0 + 6)) + tb; \
    unsigned o7 = __shfl(boff, qb + (E0 + 7)) + tb; \
    uint4 v0 = *(const uint4*)(fpb + o0); \
    uint4 v1 = *(const uint4*)(fpb + o1); \
    uint4 v2 = *(const uint4*)(fpb + o2); \
    uint4 v3 = *(const uint4*)(fpb + o3); \
    uint4 v4 = *(const uint4*)(fpb + o4); \
    uint4 v5 = *(const uint4*)(fpb + o5); \
    uint4 v6 = *(const uint4*)(fpb + o6); \
    uint4 v7 = *(const uint4*)(fpb + o7); \
    float w0 = wq[(E0 + 0) * 4 + hd]; \
    float w1 = wq[(E0 + 1) * 4 + hd]; \
    float w2 = wq[(E0 + 2) * 4 + hd]; \
    float w3 = wq[(E0 + 3) * 4 + hd]; \
    float w4 = wq[(E0 + 4) * 4 + hd]; \
    float w5 = wq[(E0 + 5) * 4 + hd]; \
    float w6 = wq[(E0 + 6) * 4 + hd]; \
    float w7 = wq[(E0 + 7) * 4 + hd]; \
    ACC1(v0, w0) ACC1(v1, w1) ACC1(v2, w2) ACC1(v3, w3) \
    ACC1(v4, w4) ACC1(v5, w5) ACC1(v6, w6) ACC1(v7, w7) }

    for (int c = 0; c < nchunk; ++c) {
        int eb = j0 + (c << 4);
        int cnt = j1 - eb;              // uniform within quarter
        int idx = eb + t;
        bool vald = idx < j1;
        int mysn = (vald && cnt > 0) ? cs[idx] : 0;
        unsigned boff = (unsigned)mysn << 8;
        if (cnt > 0) {
            float4 ev = *(const float4*)((const char*)elp + ((unsigned)mysn << 4));
            float4 wv;
            float e;
            e = ev.x + rv.x; e = fmaxf(e, NEG_SLOPE * e); wv.x = vald ? __expf(e) : 0.f;
            e = ev.y + rv.y; e = fmaxf(e, NEG_SLOPE * e); wv.y = vald ? __expf(e) : 0.f;
            e = ev.z + rv.z; e = fmaxf(e, NEG_SLOPE * e); wv.z = vald ? __expf(e) : 0.f;
            e = ev.w + rv.w; e = fmaxf(e, NEG_SLOPE * e); wv.w = vald ? __expf(e) : 0.f;
            *(float4*)&wq[t * 4] = wv;
            GROUP8(0)
        }
        if (cnt > 8) {
            GROUP8(8)
        }
    }
#undef GROUP8
#undef ACC1

    if (n < N) {
        float inv = 1.f / sumw;
        int ca0 = 32 * hd + ((4 * t) & 15);   // first of 4 consecutive cols
        const float* bp = bias + p * FF + ca0;
        float4 blo = *(const float4*)bp;
        float4 bhi = *(const float4*)(bp + 16);
        float z00 = fmaf(a00, inv, blo.x);
        float z10 = fmaf(a10, inv, blo.y);
        float z20 = fmaf(a20, inv, blo.z);
        float z30 = fmaf(a30, inv, blo.w);
        float z01 = fmaf(a01, inv, bhi.x);
        float z11 = fmaf(a11, inv, bhi.y);
        float z21 = fmaf(a21, inv, bhi.z);
        float z31 = fmaf(a31, inv, bhi.w);
        z00 = z00 > 0.f ? z00 : __expf(z00) - 1.f;
        z10 = z10 > 0.f ? z10 : __expf(z10) - 1.f;
        z20 = z20 > 0.f ? z20 : __expf(z20) - 1.f;
        z30 = z30 > 0.f ? z30 : __expf(z30) - 1.f;
        z01 = z01 > 0.f ? z01 : __expf(z01) - 1.f;
        z11 = z11 > 0.f ? z11 : __expf(z11) - 1.f;
        z21 = z21 > 0.f ? z21 : __expf(z21) - 1.f;
        z31 = z31 > 0.f ? z31 : __expf(z31) - 1.f;
        size_t zb = ((size_t)p * N + n) * FF;
        float4 lo = make_float4(z00, z10, z20, z30);
        float4 hi = make_float4(z01, z11, z21, z31);
        *(float4*)&z[zb + ca0] = lo;
        *(float4*)&z[zb + ca0 + 16] = hi;
        uint4 pk = make_uint4(bf16pair(z00, z01), bf16pair(z10, z11),
                              bf16pair(z20, z21), bf16pair(z30, z31));
        *(uint4*)&zb16[((size_t)p * N + n) * 64 + 4 * t] = pk;
    }
}

// K6: s[n,p] = tanh(z @ W1 + b1) @ W2 via bf16 MFMA (W1pack k-permuted to
// match zb16 word layout), summed per block.
__global__ __launch_bounds__(256) void k6_mfma(const unsigned int* __restrict__ zb16,
                        const unsigned short* __restrict__ W1pack,
                        const float* __restrict__ b1, const float* __restrict__ W2,
                        float* __restrict__ partials, int N) {
    __shared__ float wsum[4];
    int l = threadIdx.x & 63;
    int wu = threadIdx.x >> 6;
    int p = blockIdx.y;
    int rowbase = blockIdx.x * 64 + wu * 16;
    float ssum = 0.f;
    if (rowbase < N) {
        int q = l >> 4;
        int t16 = l & 15;
        int arow = rowbase + t16; if (arow > N - 1) arow = N - 1;
        const unsigned short* zrow =
            (const unsigned short*)(zb16 + ((size_t)p * N + arow) * 64) + q * 8;

        f32x4 acc[8];
#pragma unroll
        for (int i = 0; i < 8; ++i) acc[i] = (f32x4){0.f, 0.f, 0.f, 0.f};
#pragma unroll
        for (int ks = 0; ks < 4; ++ks) {
            bf16x8 av = *(const bf16x8*)&zrow[ks * 32];
#pragma unroll
            for (int nt = 0; nt < 8; ++nt) {
                bf16x8 bv = *(const bf16x8*)&W1pack[(((size_t)nt * 4 + ks) * 64 + l) * 8];
                acc[nt] = __builtin_amdgcn_mfma_f32_16x16x32_bf16(av, bv, acc[nt], 0, 0, 0);
            }
        }
        float b1v[8], w2v[8];
#pragma unroll
        for (int nt = 0; nt < 8; ++nt) {
            int col = nt * 16 + t16;
            b1v[nt] = b1[col];
            w2v[nt] = W2[col];
        }
        float rowsum[4] = {0.f, 0.f, 0.f, 0.f};
#pragma unroll
        for (int nt = 0; nt < 8; ++nt)
#pragma unroll
            for (int r = 0; r < 4; ++r) {
                float a = acc[nt][r] + b1v[nt];
                float e = __expf(2.f * a);
                float t = 1.f - 2.f * __builtin_amdgcn_rcpf(e + 1.f);
                rowsum[r] = fmaf(t, w2v[nt], rowsum[r]);
            }
#pragma unroll
        for (int r = 0; r < 4; ++r) {
            int row = rowbase + q * 4 + r;
            ssum += (row < N) ? rowsum[r] : 0.f;
        }
#pragma unroll
        for (int off = 32; off >= 1; off >>= 1) ssum += __shfl_xor(ssum, off);
    }
    if (l == 0) wsum[wu] = ssum;
    __syncthreads();
    if (threadIdx.x == 0)
        partials[(size_t)p * gridDim.x + blockIdx.x] = wsum[0] + wsum[1] + wsum[2] + wsum[3];
}

// K8: absorbs k7 -- each block redundantly reduces partials (9.4 KB, L2-hot)
// -> beta in LDS, then out[n,:] = sum_p beta[p] * z[p][n,:] (float4).
__global__ __launch_bounds__(256) void k8_combine(const float* __restrict__ z,
                           const float* __restrict__ partials,
                           float* __restrict__ out, int N, int nblk) {
    __shared__ float bsh[3];
    int tt = threadIdx.x;
    if (tt < 192) {
        int p = tt >> 6, l = tt & 63;
        float s = 0.f;
        for (int i = l; i < nblk; i += 64) s += partials[(size_t)p * nblk + i];
        for (int off = 32; off >= 1; off >>= 1) s += __shfl_xor(s, off);
        if (l == 0) bsh[p] = s / (float)N;
    }
    __syncthreads();
    if (tt == 0) {
        float m = fmaxf(bsh[0], fmaxf(bsh[1], bsh[2]));
        float e0 = __expf(bsh[0] - m), e1 = __expf(bsh[1] - m), e2 = __expf(bsh[2] - m);
        float inv = 1.f / (e0 + e1 + e2);
        bsh[0] = e0 * inv; bsh[1] = e1 * inv; bsh[2] = e2 * inv;
    }
    __syncthreads();
    float b0 = bsh[0], b1 = bsh[1], b2 = bsh[2];
    size_t i = (size_t)blockIdx.x * 256 + tt;
    size_t tot4 = (size_t)N * FF / 4;
    if (i < tot4) {
        const float4* z4 = (const float4*)z;
        float4 a = z4[i], b = z4[tot4 + i], c = z4[2 * tot4 + i];
        float4 o;
        o.x = b0 * a.x + b1 * b.x + b2 * c.x;
        o.y = b0 * a.y + b1 * b.y + b2 * c.y;
        o.z = b0 * a.z + b1 * b.z + b2 * c.z;
        o.w = b0 * a.w + b1 * b.w + b2 * c.w;
        ((float4*)out)[i] = o;
    }
}

extern "C" void kernel_launch(void* const* d_in, const int* in_sizes, int n_in,
                              void* d_out, int out_size, void* d_ws, size_t ws_size,
                              hipStream_t stream) {
    const float* h    = (const float*)d_in[0];
    const float* W    = (const float*)d_in[1];
    const float* al   = (const float*)d_in[2];
    const float* ar   = (const float*)d_in[3];
    const float* bias = (const float*)d_in[4];
    const float* W1   = (const float*)d_in[5];
    const float* b1   = (const float*)d_in[6];
    const float* W2   = (const float*)d_in[7];
    const int*   src  = (const int*)d_in[8];
    const int*   dst  = (const int*)d_in[9];
    float* out = (float*)d_out;

    int N = in_sizes[0] / INF_;
    int E = in_sizes[8] / PP;
    int nbuk = (N + BW - 1) >> BSHIFT;

    char* ws = (char*)d_ws;
    size_t off = 0;
    auto take = [&](size_t bytes) -> void* {
        off = (off + 255) & ~(size_t)255;
        void* ptr = ws + off;
        off += bytes;
        return ptr;
    };
    unsigned int* featb = (unsigned int*)take((size_t)PP * N * 64 * sizeof(unsigned int));
    float* z        = (float*)take((size_t)PP * N * FF * sizeof(float));
    unsigned int* zb16 = (unsigned int*)take((size_t)PP * N * 64 * sizeof(unsigned int));
    float* el       = (float*)take((size_t)PP * N * HH * sizeof(float));
    float* er       = (float*)take((size_t)PP * N * HH * sizeof(float));
    int*   offs     = (int*)take((size_t)PP * (N + 1) * sizeof(int));
    int*   csr      = (int*)take((size_t)PP * E * sizeof(int));
    unsigned int* barr = (unsigned int*)take((size_t)PP * 128 * BCAP * sizeof(unsigned int));
    int*   gcur     = (int*)take((size_t)PP * 128 * sizeof(int));
    unsigned short* hb16   = (unsigned short*)take((size_t)N * INF_ * sizeof(unsigned short));
    unsigned short* Wpack  = (unsigned short*)take((size_t)PP * 8 * 4 * 64 * 8 * sizeof(unsigned short));
    unsigned short* W1pack = (unsigned short*)take((size_t)8 * 4 * 64 * 8 * sizeof(unsigned short));
    int    nblkM    = (N + 63) / 64;
    int    nblk16   = (N + 15) / 16;
    float* partials = (float*)take((size_t)PP * nblkM * sizeof(float));
    (void)ws_size; (void)n_in; (void)out_size;

    int total4 = N * INF_ / 4;
    int khblocks = (total4 + 255) / 256;
    int packblocks = (PP * 2048 + 2048 + 255) / 256;   // = 32
    int gAx = (E + ACH * 256 - 1) / (ACH * 256);
    dim3 gM(nblkM, PP);
    dim3 gM1(nblkM + gAx, PP);
    dim3 gNode(nblk16, PP);
    dim3 gB(nbuk, PP);

    mega0<<<khblocks + packblocks, 256, 0, stream>>>(h, hb16, gcur, total4, khblocks,
                                                     W, Wpack, W1, W1pack);
    mega1<<<gM1, 256, 0, stream>>>(hb16, Wpack, al, ar, featb, el, er, N, nblkM,
                                   src, dst, gcur, barr, E);
    kB_build<<<gB, 512, 0, stream>>>(barr, gcur, offs, csr, N, E, nbuk);
    k5_aggregate<<<gNode, 256, 0, stream>>>(featb, el, er, bias, offs, csr, z, zb16, N, E);
    k6_mfma<<<gM, 256, 0, stream>>>(zb16, W1pack, b1, W2, partials, N);
    k8_combine<<<(int)(((size_t)N * FF / 4 + 255) / 256), 256, 0, stream>>>(
        z, partials, out, N, nblkM);
}